// Round 9
// baseline (168.276 us; speedup 1.0000x reference)
//
#include <hip/hip_runtime.h>
#include <hip/hip_bf16.h>

// B=128, CIN=3, H=W=32, C1=64, C2=256, NUM_CLASSES=1000
// K_CONV=48, K_FC=12451 >= 48*256 => FC reduces exactly to the 48 selected
// channels' pooled features (non-selected channels are exactly zero).
// 3 kernels (true global deps: conv1->selection, conv2->FC). Selection is
// recomputed redundantly per conv2 block (deterministic, identical result)
// to remove the k2 kernel + boundary (~20-40us each in replayed graphs).

#define NSEL 48
#define NCLS 1000

__device__ __forceinline__ unsigned short f2bf(float x) {
  unsigned u = __builtin_bit_cast(unsigned, x);
  u += 0x7fffu + ((u >> 16) & 1u);  // RNE (finite inputs)
  return (unsigned short)(u >> 16);
}

__device__ __forceinline__ void gl_lds16(const void* g, void* l) {
  __builtin_amdgcn_global_load_lds(
      (const __attribute__((address_space(1))) void*)g,
      (__attribute__((address_space(3))) void*)l, 16, 0, 0);
}

using sh8 = __attribute__((ext_vector_type(8))) short;
using f4  = __attribute__((ext_vector_type(4))) float;

// ---------------- K1: conv1 + ReLU -> x1 bf16 [b][pix][64ic]; |.| partial sums ----
__global__ __launch_bounds__(256) void k1_conv1(
    const float* __restrict__ x0, const float* __restrict__ w1,
    const float* __restrict__ b1, unsigned short* __restrict__ x1,
    float* __restrict__ part2, int* __restrict__ cnt) {
  const int b = blockIdx.x, quarter = blockIdx.y;
  const int t = threadIdx.x;
  const int wv = t >> 6;
  __shared__ float xs[3 * 320];   // 3 ic x 10 rows x 32 cols
  __shared__ float wred[64 * 4];
  const int r0 = quarter * 8;

  if (b == 0 && quarter == 0 && t < 32) cnt[t] = 0;  // for K3's fence reduction

  for (int q = 0; q < 15; ++q) {  // 3840 floats
    const int id = q * 256 + t;
    const int ic = id / 320;
    const int rem = id - ic * 320;
    const int row = rem >> 5, col = rem & 31;
    const int gr = r0 - 1 + row;
    xs[id] = ((unsigned)gr < 32u)
                 ? x0[((size_t)b * 3 + ic) * 1024 + gr * 32 + col] : 0.f;
  }
  __syncthreads();

  const int lr = t >> 5, pc = t & 31;
  float win[3][3][3];
#pragma unroll
  for (int ic = 0; ic < 3; ++ic)
#pragma unroll
    for (int kr = 0; kr < 3; ++kr)
#pragma unroll
      for (int kc = 0; kc < 3; ++kc) {
        const int cc = pc - 1 + kc;
        win[ic][kr][kc] = ((unsigned)cc < 32u) ? xs[ic * 320 + (lr + kr) * 32 + cc] : 0.f;
      }

  unsigned pk[32];
#pragma unroll
  for (int oc = 0; oc < 64; ++oc) {
    float a = b1[oc];
#pragma unroll
    for (int ic = 0; ic < 3; ++ic)
#pragma unroll
      for (int kr = 0; kr < 3; ++kr)
#pragma unroll
        for (int kc = 0; kc < 3; ++kc)
          a += w1[oc * 27 + ic * 9 + kr * 3 + kc] * win[ic][kr][kc];
    const float v = a > 0.f ? a : 0.f;
    const unsigned bf = f2bf(v);
    if (oc & 1) pk[oc >> 1] |= bf << 16; else pk[oc >> 1] = bf;
    float rs = v;
    for (int off = 32; off > 0; off >>= 1) rs += __shfl_down(rs, off, 64);
    if ((t & 63) == 0) wred[oc * 4 + wv] = rs;
  }

  {
    int4* dst = reinterpret_cast<int4*>(x1) +
                ((size_t)b * 1024 + (r0 + lr) * 32 + pc) * 8;
    const int4* src = reinterpret_cast<const int4*>(pk);
#pragma unroll
    for (int j2 = 0; j2 < 8; ++j2) dst[j2] = src[j2];
  }
  __syncthreads();
  if (t < 64) {
    const float s = wred[t * 4] + wred[t * 4 + 1] + wred[t * 4 + 2] + wred[t * 4 + 3];
    part2[((size_t)quarter * 64 + t) * 128 + b] = s;
  }
}

// ---------------- K2': redundant selection + conv2 MFMA (per-shift w gather) ------
// grid (128 b, 4 quarter) x 256 thr.
__global__ __launch_bounds__(256) void k2_conv2sel(
    const float* __restrict__ part2, const float* __restrict__ gate_w,
    const float* __restrict__ w2, const float* __restrict__ b2,
    const unsigned short* __restrict__ x1, int* __restrict__ sel,
    unsigned short* __restrict__ pooledt) {
  const int b = blockIdx.x, quarter = blockIdx.y;
  const int t = threadIdx.x;
  const int w = t >> 6, l = t & 63;
  const int q4 = l >> 4, ln15 = l & 15;
  __shared__ __align__(16) char smem[47360];
  short* xt = (short*)smem;                     // [0, 40960): staged input tile
  short* wsl = (short*)(smem + 40960);          // [40960, 47104): [48][64] bf16 shift slice
  int* sel_s = (int*)(smem + 47104);            // 48 ints

  // ---- selection (redundant per block; deterministic identical result) ----
  {
    float* red = (float*)smem;                  // 64*33 f (aliases xt region)
    float* sig = (float*)(smem + 8448);         // 64 f
    float* sc  = (float*)(smem + 8704);         // 256 f
    float prt[8];
#pragma unroll
    for (int k = 0; k < 8; ++k) prt[k] = 0.f;
    const float4* pv = reinterpret_cast<const float4*>(part2);
#pragma unroll
    for (int q = 0; q < 32; ++q) {
      const float4 v = pv[q * 256 + t];
      prt[q & 7] += v.x + v.y + v.z + v.w;
    }
#pragma unroll
    for (int k = 0; k < 8; ++k)
      red[(k * 8 + (t >> 5)) * 33 + (t & 31)] = prt[k];
    __syncthreads();
    if (t < 64) {
      float s = 0.f;
      for (int i = 0; i < 32; ++i) s += red[t * 33 + i];
      sig[t] = s * (1.0f / 131072.0f);
    }
    __syncthreads();
    {
      float lg = 0.f;
#pragma unroll 8
      for (int i = 0; i < 64; ++i) lg += gate_w[t * 64 + i] * sig[i];
      sc[t] = lg;  // softplus monotone -> rank by logits
    }
    __syncthreads();
    {
      const float v = sc[t];
      int r = 0;
      for (int i = 0; i < 256; ++i) {
        const float vi = sc[i];
        r += (vi > v) || (vi == v && i < t);
      }
      if (r < NSEL) {
        sel_s[r] = t;
        if (b == 0 && quarter == 0) sel[r] = t;  // publish for K3
      }
    }
    __syncthreads();
  }

  const int r0 = quarter * 8;

  // ---- stage halo'd x1 rows (swizzle folded into per-lane global source) ----
  for (int q = 0; q < 10; ++q) {
    const int S = (w * 10 + q) * 64 + l;
    const int pix = S >> 3, slot = S & 7;
    const int row = pix >> 5, col = pix & 31;
    int gr = r0 - 1 + row;
    gr = gr < 0 ? 0 : (gr > 31 ? 31 : gr);
    const unsigned short* gsrc =
        x1 + ((size_t)(b * 1024 + gr * 32 + col) * 64) + (slot ^ (pix & 7)) * 8;
    gl_lds16((const void*)gsrc, (void*)&xt[(w * 10 + q) * 512]);
  }
  __syncthreads();

  f4 acc[4][3];
  const f4 fz = {0.f, 0.f, 0.f, 0.f};
#pragma unroll
  for (int i = 0; i < 4; ++i)
#pragma unroll
    for (int nt = 0; nt < 3; ++nt) acc[i][nt] = fz;

  const int w4 = w * 4;
  const sh8 zz = {0, 0, 0, 0, 0, 0, 0, 0};

  for (int sh = 0; sh < 9; ++sh) {
    const int kh = sh / 3, kw = sh - kh * 3;
    if (sh) __syncthreads();  // all waves done reading previous wsl
    // gather this shift's weights: wsl[j][ic] = bf16(w2[sel[j]][ic][sh])
#pragma unroll
    for (int k = 0; k < 12; ++k) {
      const int idx = k * 256 + t;  // 0..3071
      const int j = idx >> 6, ic = idx & 63;
      wsl[idx] = f2bf(w2[(size_t)sel_s[j] * 576 + ic * 9 + sh]);
    }
    __syncthreads();

    sh8 bf[3][2];
#pragma unroll
    for (int nt = 0; nt < 3; ++nt)
#pragma unroll
      for (int ks = 0; ks < 2; ++ks)
        bf[nt][ks] = *reinterpret_cast<const sh8*>(
            &wsl[(nt * 16 + ln15) * 64 + ks * 32 + q4 * 8]);
#pragma unroll
    for (int i = 0; i < 4; ++i) {
      const int mt = w4 + i;
      const int lsr = (mt >> 1) + kh;
      const int gsr = r0 + lsr - 1;
      if ((unsigned)gsr < 32u) {  // wave-uniform
        const int w_ = (mt & 1) * 16 + ln15;
        const int cc = w_ + kw - 1;
        const bool cv = (unsigned)cc < 32u;
        int p = lsr * 32 + cc;
        p = p < 0 ? 0 : (p > 319 ? 319 : p);
#pragma unroll
        for (int ks = 0; ks < 2; ++ks) {
          sh8 af = *reinterpret_cast<const sh8*>(
              &xt[p * 64 + (((ks << 2) | q4) ^ (p & 7)) * 8]);
          af = cv ? af : zz;
          acc[i][0] = __builtin_amdgcn_mfma_f32_16x16x32_bf16(af, bf[0][ks], acc[i][0], 0, 0, 0);
          acc[i][1] = __builtin_amdgcn_mfma_f32_16x16x32_bf16(af, bf[1][ks], acc[i][1], 0, 0, 0);
          acc[i][2] = __builtin_amdgcn_mfma_f32_16x16x32_bf16(af, bf[2][ks], acc[i][2], 0, 0, 0);
        }
      }
    }
  }

  __syncthreads();  // done with xt/wsl; reuse smem as pooled staging [48 oc][64 p]

  float bias[3];
#pragma unroll
  for (int nt = 0; nt < 3; ++nt) bias[nt] = b2[sel_s[nt * 16 + ln15]];

  unsigned short* ps = reinterpret_cast<unsigned short*>(smem);
#pragma unroll
  for (int a = 0; a < 2; ++a) {
#pragma unroll
    for (int nt = 0; nt < 3; ++nt) {
      const f4 A = acc[a][nt], Bv = acc[a + 2][nt];
#pragma unroll
      for (int pr = 0; pr < 2; ++pr) {
        float m = fmaxf(fmaxf(A[pr * 2], A[pr * 2 + 1]),
                        fmaxf(Bv[pr * 2], Bv[pr * 2 + 1]));
        m = fmaxf(m + bias[nt], 0.f);
        const int pl = w * 16 + a * 8 + q4 * 2 + pr;
        ps[(nt * 16 + ln15) * 64 + pl] = f2bf(m);
      }
    }
  }
  __syncthreads();

  const int4* psv = reinterpret_cast<const int4*>(smem);
  int4* po = reinterpret_cast<int4*>(pooledt);
  for (int c = t; c < 384; c += 256) {
    const int j = c >> 3, sub = c & 7;
    po[(size_t)(j * 32 + quarter * 8 + sub) * 128 + b] = psv[c];
  }
}

// ---------------- K3: FC bf16 MFMA partials + threadfence-fused reduction ---------
// grid (32 ntile, 16 ks). Last-finishing block per ntile reduces + writes out.
__global__ __launch_bounds__(256) void k4_fc(
    const unsigned short* __restrict__ pooledt, const float* __restrict__ fc_w,
    const int* __restrict__ sel, const float* __restrict__ fc_b,
    float* __restrict__ fcpart, int* __restrict__ cnt,
    float* __restrict__ out) {
  const int ntile = blockIdx.x;  // 0..31
  const int ks = blockIdx.y;     // 0..15 (K chunk = 768 = 3 channels)
  const int t = threadIdx.x;
  const int w = t >> 6, l = t & 63;

  __shared__ short Ab[2][8 * 129 * 8];  // [ko][m pad129][8]
  __shared__ short Bb[2][8 * 33 * 8];   // [ko][n pad33][8]
  __shared__ int done;

  f4 acc00 = {0.f, 0.f, 0.f, 0.f}, acc01 = acc00, acc10 = acc00, acc11 = acc00;

  int ch[3];
#pragma unroll
  for (int i = 0; i < 3; ++i)
    ch[i] = __builtin_amdgcn_readfirstlane(sel[ks * 3 + i]);

  const int n0 = ntile * 32;
  const int nrow = t >> 3, koct = t & 7;
  int ng = n0 + nrow; if (ng > 999) ng = 999;  // clamp (cols >=1000 skipped below)
  const float* wbase = fc_w + (size_t)ng * 65536 + koct * 8;

  const int4* pt = reinterpret_cast<const int4*>(pooledt);
  const int kb0 = ks * 96;

  int4 av[4];
  float4 bv0, bv1;

  {  // stage tile 0
#pragma unroll
    for (int it = 0; it < 4; ++it) {
      const int s = it * 256 + t;
      av[it] = pt[(kb0 + (s >> 7)) * 128 + (s & 127)];
    }
    const float* bp = wbase + ch[0] * 256;
    bv0 = *reinterpret_cast<const float4*>(bp);
    bv1 = *reinterpret_cast<const float4*>(bp + 4);
#pragma unroll
    for (int it = 0; it < 4; ++it) {
      const int s = it * 256 + t;
      *reinterpret_cast<int4*>(&Ab[0][((s >> 7) * 129 + (s & 127)) * 8]) = av[it];
    }
    int4 bw;
    bw.x = f2bf(bv0.x) | ((unsigned)f2bf(bv0.y) << 16);
    bw.y = f2bf(bv0.z) | ((unsigned)f2bf(bv0.w) << 16);
    bw.z = f2bf(bv1.x) | ((unsigned)f2bf(bv1.y) << 16);
    bw.w = f2bf(bv1.z) | ((unsigned)f2bf(bv1.w) << 16);
    *reinterpret_cast<int4*>(&Bb[0][(koct * 33 + nrow) * 8]) = bw;
  }
  __syncthreads();

  for (int tt = 0; tt < 12; ++tt) {
    const int cur = tt & 1, nxt = cur ^ 1;
    if (tt < 11) {
      const int tn = tt + 1;
#pragma unroll
      for (int it = 0; it < 4; ++it) {
        const int s = it * 256 + t;
        av[it] = pt[(kb0 + tn * 8 + (s >> 7)) * 128 + (s & 127)];
      }
      const float* bp = wbase + ch[tn >> 2] * 256 + (tn & 3) * 64;
      bv0 = *reinterpret_cast<const float4*>(bp);
      bv1 = *reinterpret_cast<const float4*>(bp + 4);
    }

#pragma unroll
    for (int s2 = 0; s2 < 2; ++s2) {
      const int kg = s2 * 4 + (l >> 4);
      const int m0 = w * 32 + (l & 15);
      sh8 a0 = *reinterpret_cast<const sh8*>(&Ab[cur][(kg * 129 + m0) * 8]);
      sh8 a1 = *reinterpret_cast<const sh8*>(&Ab[cur][(kg * 129 + m0 + 16) * 8]);
      sh8 b0 = *reinterpret_cast<const sh8*>(&Bb[cur][(kg * 33 + (l & 15)) * 8]);
      sh8 b1 = *reinterpret_cast<const sh8*>(&Bb[cur][(kg * 33 + 16 + (l & 15)) * 8]);
      acc00 = __builtin_amdgcn_mfma_f32_16x16x32_bf16(a0, b0, acc00, 0, 0, 0);
      acc01 = __builtin_amdgcn_mfma_f32_16x16x32_bf16(a0, b1, acc01, 0, 0, 0);
      acc10 = __builtin_amdgcn_mfma_f32_16x16x32_bf16(a1, b0, acc10, 0, 0, 0);
      acc11 = __builtin_amdgcn_mfma_f32_16x16x32_bf16(a1, b1, acc11, 0, 0, 0);
    }

    if (tt < 11) {
#pragma unroll
      for (int it = 0; it < 4; ++it) {
        const int s = it * 256 + t;
        *reinterpret_cast<int4*>(&Ab[nxt][((s >> 7) * 129 + (s & 127)) * 8]) = av[it];
      }
      int4 bw;
      bw.x = f2bf(bv0.x) | ((unsigned)f2bf(bv0.y) << 16);
      bw.y = f2bf(bv0.z) | ((unsigned)f2bf(bv0.w) << 16);
      bw.z = f2bf(bv1.x) | ((unsigned)f2bf(bv1.y) << 16);
      bw.w = f2bf(bv1.z) | ((unsigned)f2bf(bv1.w) << 16);
      *reinterpret_cast<int4*>(&Bb[nxt][(koct * 33 + nrow) * 8]) = bw;
    }
    __syncthreads();
  }

  {  // write this block's partial slice
    const int r0 = (l >> 4) * 4;
#pragma unroll
    for (int fm = 0; fm < 2; ++fm)
#pragma unroll
      for (int fn = 0; fn < 2; ++fn)
#pragma unroll
        for (int r = 0; r < 4; ++r) {
          const int m = w * 32 + fm * 16 + r0 + r;
          const int nc = n0 + fn * 16 + (l & 15);
          const f4 a = fm == 0 ? (fn == 0 ? acc00 : acc01) : (fn == 0 ? acc10 : acc11);
          fcpart[(((size_t)ks * 128 + m) << 10) + nc] = a[r];
        }
  }

  // threadfence reduction: 16th finisher per ntile sums partials + bias -> out
  __threadfence();
  if (t == 0) done = atomicAdd(&cnt[ntile], 1);
  __syncthreads();
  if (done == 15) {
    __threadfence();
#pragma unroll
    for (int it = 0; it < 16; ++it) {
      const int idx = it * 256 + t;       // 0..4095
      const int m = idx >> 5, nc = idx & 31;
      const int n = n0 + nc;
      if (n < NCLS) {
        float s = fc_b[n];
#pragma unroll
        for (int kr = 0; kr < 16; ++kr)
          s += fcpart[(((size_t)kr * 128 + m) << 10) + n];
        out[m * NCLS + n] = s;
      }
    }
  }
}

extern "C" void kernel_launch(void* const* d_in, const int* in_sizes, int n_in,
                              void* d_out, int out_size, void* d_ws, size_t ws_size,
                              hipStream_t stream) {
  (void)in_sizes; (void)n_in; (void)out_size; (void)ws_size;
  const float* x0     = (const float*)d_in[0];
  const float* w1     = (const float*)d_in[1];
  const float* b1     = (const float*)d_in[2];
  const float* gate_w = (const float*)d_in[3];
  const float* w2     = (const float*)d_in[4];
  const float* b2     = (const float*)d_in[5];
  const float* fc_w   = (const float*)d_in[6];
  const float* fc_b   = (const float*)d_in[7];
  float* out = (float*)d_out;

  char* ws = (char*)d_ws;
  unsigned short* x1      = (unsigned short*)(ws);             // 16,777,216 B
  unsigned short* pooledt = (unsigned short*)(ws + 16777216);  //  3,145,728 B
  float*          part2   = (float*)(ws + 19922944);           //    131,072 B
  int*            sel     = (int*)  (ws + 20054016);           //        256 B
  int*            cnt     = (int*)  (ws + 20054272);           //        128 B
  float*          fcpart  = (float*)(ws + 20054400);           //  8,388,608 B

  hipLaunchKernelGGL(k1_conv1, dim3(128, 4), dim3(256), 0, stream, x0, w1, b1, x1, part2, cnt);
  hipLaunchKernelGGL(k2_conv2sel, dim3(128, 4), dim3(256), 0, stream, part2, gate_w, w2, b2, x1, sel, pooledt);
  hipLaunchKernelGGL(k4_fc, dim3(32, 16), dim3(256), 0, stream, pooledt, fc_w, sel, fc_b, fcpart, cnt, out);
}

// Round 10
// 112.100 us; speedup vs baseline: 1.5011x; 1.5011x over previous
//
#include <hip/hip_runtime.h>
#include <hip/hip_bf16.h>

// B=128, CIN=3, H=W=32, C1=64, C2=256, NUM_CLASSES=1000
// K_CONV=48, K_FC=12451 >= 48*256 => FC reduces exactly to the 48 selected
// channels' pooled features (non-selected channels are exactly zero).
// R3-verbatim re-anchor: best measured config (112 us). Rounds 4-9 fusions
// (threadfence k5-fold, redundant selection, depth-2 prefetch) all measured
// worse; this run disambiguates structure-cost vs run-to-run noise.

#define NSEL 48
#define NCLS 1000

__device__ __forceinline__ unsigned short f2bf(float x) {
  unsigned u = __builtin_bit_cast(unsigned, x);
  u += 0x7fffu + ((u >> 16) & 1u);  // RNE (finite inputs)
  return (unsigned short)(u >> 16);
}

__device__ __forceinline__ void gl_lds16(const void* g, void* l) {
  __builtin_amdgcn_global_load_lds(
      (const __attribute__((address_space(1))) void*)g,
      (__attribute__((address_space(3))) void*)l, 16, 0, 0);
}

using sh8 = __attribute__((ext_vector_type(8))) short;
using f4  = __attribute__((ext_vector_type(4))) float;

// ---------------- K1: conv1 + ReLU -> x1 bf16 [b][pix][64ic]; |.| partial sums ----
// grid (128 b, 4 quarter), 256 thr; quarter = 8 output rows.
__global__ __launch_bounds__(256) void k1_conv1(
    const float* __restrict__ x0, const float* __restrict__ w1,
    const float* __restrict__ b1, unsigned short* __restrict__ x1,
    float* __restrict__ part2) {
  const int b = blockIdx.x, quarter = blockIdx.y;
  const int t = threadIdx.x;
  const int wv = t >> 6;
  __shared__ float xs[3 * 320];   // 3 ic x 10 rows x 32 cols
  __shared__ float wred[64 * 4];
  const int r0 = quarter * 8;

  for (int q = 0; q < 15; ++q) {  // 3840 floats
    const int id = q * 256 + t;
    const int ic = id / 320;
    const int rem = id - ic * 320;
    const int row = rem >> 5, col = rem & 31;
    const int gr = r0 - 1 + row;
    xs[id] = ((unsigned)gr < 32u)
                 ? x0[((size_t)b * 3 + ic) * 1024 + gr * 32 + col] : 0.f;
  }
  __syncthreads();

  const int lr = t >> 5, pc = t & 31;  // local out row 0..7, col 0..31
  float win[3][3][3];
#pragma unroll
  for (int ic = 0; ic < 3; ++ic)
#pragma unroll
    for (int kr = 0; kr < 3; ++kr)
#pragma unroll
      for (int kc = 0; kc < 3; ++kc) {
        const int cc = pc - 1 + kc;
        win[ic][kr][kc] = ((unsigned)cc < 32u) ? xs[ic * 320 + (lr + kr) * 32 + cc] : 0.f;
      }

  unsigned pk[32];
#pragma unroll
  for (int oc = 0; oc < 64; ++oc) {
    float a = b1[oc];
#pragma unroll
    for (int ic = 0; ic < 3; ++ic)
#pragma unroll
      for (int kr = 0; kr < 3; ++kr)
#pragma unroll
        for (int kc = 0; kc < 3; ++kc)
          a += w1[oc * 27 + ic * 9 + kr * 3 + kc] * win[ic][kr][kc];
    const float v = a > 0.f ? a : 0.f;
    const unsigned bf = f2bf(v);
    if (oc & 1) pk[oc >> 1] |= bf << 16; else pk[oc >> 1] = bf;
    float rs = v;
    for (int off = 32; off > 0; off >>= 1) rs += __shfl_down(rs, off, 64);
    if ((t & 63) == 0) wred[oc * 4 + wv] = rs;
  }

  {  // write one 128-B ic-row per thread
    int4* dst = reinterpret_cast<int4*>(x1) +
                ((size_t)b * 1024 + (r0 + lr) * 32 + pc) * 8;
    const int4* src = reinterpret_cast<const int4*>(pk);
#pragma unroll
    for (int j2 = 0; j2 < 8; ++j2) dst[j2] = src[j2];
  }
  __syncthreads();
  if (t < 64) {
    const float s = wred[t * 4] + wred[t * 4 + 1] + wred[t * 4 + 2] + wred[t * 4 + 3];
    part2[((size_t)quarter * 64 + t) * 128 + b] = s;
  }
}

// ---------------- K2: sig -> gate logits -> top-48 selection ----------------------
__global__ __launch_bounds__(256) void k2_select(
    const float* __restrict__ part2, const float* __restrict__ gate_w,
    int* __restrict__ sel) {
  const int t = threadIdx.x;
  __shared__ float red[256];
  __shared__ float sig[64];
  __shared__ float sc[256];
  __shared__ int flag[256];
  {
    const int c = t >> 2, q = t & 3;
    float s = 0.f;
    for (int h = 0; h < 4; ++h)
      for (int i = 0; i < 32; ++i)
        s += part2[((size_t)h * 64 + c) * 128 + q * 32 + i];
    red[t] = s;
  }
  __syncthreads();
  if (t < 64)
    sig[t] = (red[4 * t] + red[4 * t + 1] + red[4 * t + 2] + red[4 * t + 3]) *
             (1.0f / 131072.0f);
  __syncthreads();
  {
    float lg = 0.f;
    for (int i = 0; i < 64; ++i) lg += gate_w[t * 64 + i] * sig[i];
    sc[t] = lg;  // softplus monotone -> rank by logits
  }
  __syncthreads();
  {
    const float v = sc[t];
    int r = 0;
    for (int j = 0; j < 256; ++j) {
      const float vj = sc[j];
      r += (vj > v) || (vj == v && j < t);
    }
    flag[t] = (r < NSEL) ? 1 : 0;
  }
  __syncthreads();
  if (flag[t]) {
    int pos = 0;
    for (int j = 0; j < t; ++j) pos += flag[j];
    sel[pos] = t;
  }
}

// ---------------- K2b: gather/transpose conv2 weights -> w2t[9][48][64] bf16 ------
__global__ __launch_bounds__(256) void k2b_wprep(
    const float* __restrict__ w2, const float* __restrict__ b2,
    const int* __restrict__ sel, unsigned short* __restrict__ w2t,
    float* __restrict__ b2s) {
  const int j = blockIdx.x;  // 0..47 selection slot
  const int t = threadIdx.x;
  const int c = sel[j];
  if (t == 0) b2s[j] = b2[c];
  for (int id = t; id < 576; id += 256) {
    const float v = w2[(size_t)c * 576 + id];
    const int ic = id / 9;
    const int s = id - ic * 9;
    w2t[((size_t)s * 48 + j) * 64 + ic] = f2bf(v);
  }
}

// ---------------- K3: conv2 via 9-shift bf16 MFMA + bias + ReLU + maxpool ---------
// grid (128 b, 4 quarter), 256 thr (4 waves). M=256 pix (8 rows), N=48, K=64 x 9.
__global__ __launch_bounds__(256) void k3_conv2(
    const unsigned short* __restrict__ x1, const unsigned short* __restrict__ w2t,
    const float* __restrict__ b2s, unsigned short* __restrict__ pooledt) {
  const int b = blockIdx.x, quarter = blockIdx.y;
  const int t = threadIdx.x;
  const int w = t >> 6, l = t & 63;
  const int q4 = l >> 4, ln15 = l & 15;
  __shared__ short xt[20480];  // 10 rows x 32 cols x 64 ic bf16, 16B-slot swizzled

  const int r0 = quarter * 8;

  // stage halo'd rows: LDS linear, swizzle folded into per-lane global source
  for (int q = 0; q < 10; ++q) {
    const int S = (w * 10 + q) * 64 + l;  // 16B-slot id 0..2559
    const int pix = S >> 3, slot = S & 7;
    const int row = pix >> 5, col = pix & 31;
    int gr = r0 - 1 + row;
    gr = gr < 0 ? 0 : (gr > 31 ? 31 : gr);  // clamped rows masked at use
    const unsigned short* gsrc =
        x1 + ((size_t)(b * 1024 + gr * 32 + col) * 64) + (slot ^ (pix & 7)) * 8;
    gl_lds16((const void*)gsrc, (void*)&xt[(w * 10 + q) * 512]);
  }
  __syncthreads();

  f4 acc[4][3];
  const f4 fz = {0.f, 0.f, 0.f, 0.f};
#pragma unroll
  for (int i = 0; i < 4; ++i)
#pragma unroll
    for (int nt = 0; nt < 3; ++nt) acc[i][nt] = fz;

  const int w4 = w * 4;
  const sh8 zz = {0, 0, 0, 0, 0, 0, 0, 0};

#pragma unroll
  for (int kh = 0; kh < 3; ++kh)
#pragma unroll
    for (int kw = 0; kw < 3; ++kw) {
      const int sh = kh * 3 + kw;
      sh8 bf[3][2];
#pragma unroll
      for (int nt = 0; nt < 3; ++nt)
#pragma unroll
        for (int ks = 0; ks < 2; ++ks)
          bf[nt][ks] = *reinterpret_cast<const sh8*>(
              w2t + ((size_t)(sh * 48 + nt * 16 + ln15) * 64 + ks * 32 + q4 * 8));
#pragma unroll
      for (int i = 0; i < 4; ++i) {
        const int mt = w4 + i;
        const int lsr = (mt >> 1) + kh;      // local src row 0..9
        const int gsr = r0 + lsr - 1;        // global image row
        if ((unsigned)gsr < 32u) {           // wave-uniform
          const int w_ = (mt & 1) * 16 + ln15;
          const int cc = w_ + kw - 1;
          const bool cv = (unsigned)cc < 32u;
          int p = lsr * 32 + cc;
          p = p < 0 ? 0 : (p > 319 ? 319 : p);
#pragma unroll
          for (int ks = 0; ks < 2; ++ks) {
            sh8 af = *reinterpret_cast<const sh8*>(
                &xt[p * 64 + (((ks << 2) | q4) ^ (p & 7)) * 8]);
            af = cv ? af : zz;
            acc[i][0] = __builtin_amdgcn_mfma_f32_16x16x32_bf16(af, bf[0][ks], acc[i][0], 0, 0, 0);
            acc[i][1] = __builtin_amdgcn_mfma_f32_16x16x32_bf16(af, bf[1][ks], acc[i][1], 0, 0, 0);
            acc[i][2] = __builtin_amdgcn_mfma_f32_16x16x32_bf16(af, bf[2][ks], acc[i][2], 0, 0, 0);
          }
        }
      }
    }

  __syncthreads();  // done reading xt; reuse as pooled staging [48 oc][64 p]

  float bias[3];
#pragma unroll
  for (int nt = 0; nt < 3; ++nt) bias[nt] = b2s[nt * 16 + ln15];

  unsigned short* ps = reinterpret_cast<unsigned short*>(xt);
#pragma unroll
  for (int a = 0; a < 2; ++a) {
#pragma unroll
    for (int nt = 0; nt < 3; ++nt) {
      const f4 A = acc[a][nt], Bv = acc[a + 2][nt];
#pragma unroll
      for (int pr = 0; pr < 2; ++pr) {
        float m = fmaxf(fmaxf(A[pr * 2], A[pr * 2 + 1]),
                        fmaxf(Bv[pr * 2], Bv[pr * 2 + 1]));
        m = fmaxf(m + bias[nt], 0.f);
        const int pl = w * 16 + a * 8 + q4 * 2 + pr;  // 0..63 pooled idx in quarter
        ps[(nt * 16 + ln15) * 64 + pl] = f2bf(m);
      }
    }
  }
  __syncthreads();

  const int4* psv = reinterpret_cast<const int4*>(xt);
  int4* po = reinterpret_cast<int4*>(pooledt);
  for (int c = t; c < 384; c += 256) {
    const int j = c >> 3, sub = c & 7;
    po[(size_t)(j * 32 + quarter * 8 + sub) * 128 + b] = psv[c];
  }
}

// ---------------- K4: bf16 MFMA GEMM partials. BM=128, BN=32, K split 16 ----------
__global__ __launch_bounds__(256) void k4_fc(
    const unsigned short* __restrict__ pooledt, const float* __restrict__ fc_w,
    const int* __restrict__ sel, float* __restrict__ fcpart) {
  const int ntile = blockIdx.x;  // 0..31  (BN=32)
  const int ks = blockIdx.y;     // 0..15  (K chunk = 768 = 3 channels)
  const int t = threadIdx.x;
  const int w = t >> 6, l = t & 63;

  __shared__ short Ab[2][8192];  // [ko 8][m 128][8] bf16
  __shared__ short Bb[2][2048];  // [ko 8][n 32][8] bf16

  f4 acc[2][2];
  const f4 fzero = {0.f, 0.f, 0.f, 0.f};
#pragma unroll
  for (int i = 0; i < 2; ++i)
#pragma unroll
    for (int j = 0; j < 2; ++j) acc[i][j] = fzero;

  int ch[3];
#pragma unroll
  for (int i = 0; i < 3; ++i)
    ch[i] = __builtin_amdgcn_readfirstlane(sel[ks * 3 + i]);

  const int n0 = ntile * 32;
  const int nl = t & 31;
  int ng = n0 + nl; if (ng > 999) ng = 999;  // clamp tail rows (k5 ignores)
  const int kh = t >> 5;  // 0..7 k-oct
  const float* wrow = fc_w + (size_t)ng * 65536 + kh * 8;

  const int4* pt = reinterpret_cast<const int4*>(pooledt);
  const int kb0 = ks * 96;

  int4 av[4];
  float4 bv0, bv1;

  {  // stage tile 0
#pragma unroll
    for (int it = 0; it < 4; ++it) {
      const int s = it * 256 + t, ko = s >> 7, m = s & 127;
      av[it] = pt[(kb0 + ko) * 128 + m];
    }
    const float* bp = wrow + ch[0] * 256;
    bv0 = *reinterpret_cast<const float4*>(bp);
    bv1 = *reinterpret_cast<const float4*>(bp + 4);
#pragma unroll
    for (int it = 0; it < 4; ++it)
      *reinterpret_cast<int4*>(&Ab[0][(it * 256 + t) * 8]) = av[it];
    int4 bw;
    bw.x = f2bf(bv0.x) | ((unsigned)f2bf(bv0.y) << 16);
    bw.y = f2bf(bv0.z) | ((unsigned)f2bf(bv0.w) << 16);
    bw.z = f2bf(bv1.x) | ((unsigned)f2bf(bv1.y) << 16);
    bw.w = f2bf(bv1.z) | ((unsigned)f2bf(bv1.w) << 16);
    *reinterpret_cast<int4*>(&Bb[0][(kh * 32 + nl) * 8]) = bw;
  }
  __syncthreads();

  for (int tt = 0; tt < 12; ++tt) {
    const int cur = tt & 1, nxt = cur ^ 1;
    if (tt < 11) {
      const int tn = tt + 1;
#pragma unroll
      for (int it = 0; it < 4; ++it) {
        const int s = it * 256 + t, ko = s >> 7, m = s & 127;
        av[it] = pt[(kb0 + tn * 8 + ko) * 128 + m];
      }
      const float* bp = wrow + ch[tn >> 2] * 256 + (tn & 3) * 64;
      bv0 = *reinterpret_cast<const float4*>(bp);
      bv1 = *reinterpret_cast<const float4*>(bp + 4);
    }

#pragma unroll
    for (int s2 = 0; s2 < 2; ++s2) {
      const int kg = s2 * 4 + (l >> 4);
      const int m0 = w * 32 + (l & 15);
      sh8 a0 = *reinterpret_cast<const sh8*>(&Ab[cur][(kg * 128 + m0) * 8]);
      sh8 a1 = *reinterpret_cast<const sh8*>(&Ab[cur][(kg * 128 + m0 + 16) * 8]);
      sh8 b0 = *reinterpret_cast<const sh8*>(&Bb[cur][(kg * 32 + (l & 15)) * 8]);
      sh8 b1 = *reinterpret_cast<const sh8*>(&Bb[cur][(kg * 32 + 16 + (l & 15)) * 8]);
      acc[0][0] = __builtin_amdgcn_mfma_f32_16x16x32_bf16(a0, b0, acc[0][0], 0, 0, 0);
      acc[0][1] = __builtin_amdgcn_mfma_f32_16x16x32_bf16(a0, b1, acc[0][1], 0, 0, 0);
      acc[1][0] = __builtin_amdgcn_mfma_f32_16x16x32_bf16(a1, b0, acc[1][0], 0, 0, 0);
      acc[1][1] = __builtin_amdgcn_mfma_f32_16x16x32_bf16(a1, b1, acc[1][1], 0, 0, 0);
    }

    if (tt < 11) {
#pragma unroll
      for (int it = 0; it < 4; ++it)
        *reinterpret_cast<int4*>(&Ab[nxt][(it * 256 + t) * 8]) = av[it];
      int4 bw;
      bw.x = f2bf(bv0.x) | ((unsigned)f2bf(bv0.y) << 16);
      bw.y = f2bf(bv0.z) | ((unsigned)f2bf(bv0.w) << 16);
      bw.z = f2bf(bv1.x) | ((unsigned)f2bf(bv1.y) << 16);
      bw.w = f2bf(bv1.z) | ((unsigned)f2bf(bv1.w) << 16);
      *reinterpret_cast<int4*>(&Bb[nxt][(kh * 32 + nl) * 8]) = bw;
    }
    __syncthreads();
  }

  const int r0 = (l >> 4) * 4;
#pragma unroll
  for (int fm = 0; fm < 2; ++fm)
#pragma unroll
    for (int fn = 0; fn < 2; ++fn)
#pragma unroll
      for (int r = 0; r < 4; ++r) {
        const int m = w * 32 + fm * 16 + r0 + r;
        const int nc = n0 + fn * 16 + (l & 15);
        fcpart[(((size_t)ks * 128 + m) << 10) + nc] = acc[fm][fn][r];
      }
}

// ---------------- K5: reduce K-split partials + bias ------------------------------
__global__ __launch_bounds__(256) void k5_reduce(
    const float* __restrict__ fcpart, const float* __restrict__ fc_b,
    float* __restrict__ out) {
  const int id = blockIdx.x * 256 + threadIdx.x;  // 0..127999
  const int b = id / 1000;
  const int n = id - b * 1000;
  float s = fc_b[n];
#pragma unroll
  for (int ks = 0; ks < 16; ++ks)
    s += fcpart[(((size_t)ks * 128 + b) << 10) + n];
  out[id] = s;
}

extern "C" void kernel_launch(void* const* d_in, const int* in_sizes, int n_in,
                              void* d_out, int out_size, void* d_ws, size_t ws_size,
                              hipStream_t stream) {
  (void)in_sizes; (void)n_in; (void)out_size; (void)ws_size;
  const float* x0     = (const float*)d_in[0];
  const float* w1     = (const float*)d_in[1];
  const float* b1     = (const float*)d_in[2];
  const float* gate_w = (const float*)d_in[3];
  const float* w2     = (const float*)d_in[4];
  const float* b2     = (const float*)d_in[5];
  const float* fc_w   = (const float*)d_in[6];
  const float* fc_b   = (const float*)d_in[7];
  float* out = (float*)d_out;

  char* ws = (char*)d_ws;
  unsigned short* x1      = (unsigned short*)(ws);             // 16,777,216 B
  unsigned short* pooledt = (unsigned short*)(ws + 16777216);  //  3,145,728 B
  float*          part2   = (float*)(ws + 19922944);           //    131,072 B
  int*            sel     = (int*)  (ws + 20054016);           //        256 B
  unsigned short* w2t     = (unsigned short*)(ws + 20054272);  //     55,296 B
  float*          b2s     = (float*)(ws + 20109568);           //        768 B
  float*          fcpart  = (float*)(ws + 20110336);           //  8,388,608 B

  hipLaunchKernelGGL(k1_conv1, dim3(128, 4), dim3(256), 0, stream, x0, w1, b1, x1, part2);
  hipLaunchKernelGGL(k2_select, dim3(1), dim3(256), 0, stream, part2, gate_w, sel);
  hipLaunchKernelGGL(k2b_wprep, dim3(48), dim3(256), 0, stream, w2, b2, sel, w2t, b2s);
  hipLaunchKernelGGL(k3_conv2, dim3(128, 4), dim3(256), 0, stream, x1, w2t, b2s, pooledt);
  hipLaunchKernelGGL(k4_fc, dim3(32, 16), dim3(256), 0, stream, pooledt, fc_w, sel, fcpart);
  hipLaunchKernelGGL(k5_reduce, dim3(500), dim3(256), 0, stream, fcpart, fc_b, out);
}

// Round 11
// 107.371 us; speedup vs baseline: 1.5672x; 1.0440x over previous
//
#include <hip/hip_runtime.h>
#include <hip/hip_bf16.h>

// B=128, CIN=3, H=W=32, C1=64, C2=256, NUM_CLASSES=1000
// K_CONV=48, K_FC=12451 >= 48*256 => FC reduces exactly to the 48 selected
// channels' pooled features (non-selected channels are exactly zero).
// Slot order = gate-score rank order; FC sum is order-invariant.
// R10 (=R3, 112us reproduced +-1us) with ONE change: k2+k2b merged into the
// 48-block selprep (node 6->5). Boundary ~= 14us/node; fences/redundancy
// mechanisms measured more expensive than boundaries -> only clean merges.

#define NSEL 48
#define NCLS 1000

__device__ __forceinline__ unsigned short f2bf(float x) {
  unsigned u = __builtin_bit_cast(unsigned, x);
  u += 0x7fffu + ((u >> 16) & 1u);  // RNE (finite inputs)
  return (unsigned short)(u >> 16);
}

__device__ __forceinline__ void gl_lds16(const void* g, void* l) {
  __builtin_amdgcn_global_load_lds(
      (const __attribute__((address_space(1))) void*)g,
      (__attribute__((address_space(3))) void*)l, 16, 0, 0);
}

using sh8 = __attribute__((ext_vector_type(8))) short;
using f4  = __attribute__((ext_vector_type(4))) float;

// ---------------- K1: conv1 + ReLU -> x1 bf16 [b][pix][64ic]; |.| partial sums ----
__global__ __launch_bounds__(256) void k1_conv1(
    const float* __restrict__ x0, const float* __restrict__ w1,
    const float* __restrict__ b1, unsigned short* __restrict__ x1,
    float* __restrict__ part2) {
  const int b = blockIdx.x, quarter = blockIdx.y;
  const int t = threadIdx.x;
  const int wv = t >> 6;
  __shared__ float xs[3 * 320];   // 3 ic x 10 rows x 32 cols
  __shared__ float wred[64 * 4];
  const int r0 = quarter * 8;

  for (int q = 0; q < 15; ++q) {  // 3840 floats
    const int id = q * 256 + t;
    const int ic = id / 320;
    const int rem = id - ic * 320;
    const int row = rem >> 5, col = rem & 31;
    const int gr = r0 - 1 + row;
    xs[id] = ((unsigned)gr < 32u)
                 ? x0[((size_t)b * 3 + ic) * 1024 + gr * 32 + col] : 0.f;
  }
  __syncthreads();

  const int lr = t >> 5, pc = t & 31;
  float win[3][3][3];
#pragma unroll
  for (int ic = 0; ic < 3; ++ic)
#pragma unroll
    for (int kr = 0; kr < 3; ++kr)
#pragma unroll
      for (int kc = 0; kc < 3; ++kc) {
        const int cc = pc - 1 + kc;
        win[ic][kr][kc] = ((unsigned)cc < 32u) ? xs[ic * 320 + (lr + kr) * 32 + cc] : 0.f;
      }

  unsigned pk[32];
#pragma unroll
  for (int oc = 0; oc < 64; ++oc) {
    float a = b1[oc];
#pragma unroll
    for (int ic = 0; ic < 3; ++ic)
#pragma unroll
      for (int kr = 0; kr < 3; ++kr)
#pragma unroll
        for (int kc = 0; kc < 3; ++kc)
          a += w1[oc * 27 + ic * 9 + kr * 3 + kc] * win[ic][kr][kc];
    const float v = a > 0.f ? a : 0.f;
    const unsigned bf = f2bf(v);
    if (oc & 1) pk[oc >> 1] |= bf << 16; else pk[oc >> 1] = bf;
    float rs = v;
    for (int off = 32; off > 0; off >>= 1) rs += __shfl_down(rs, off, 64);
    if ((t & 63) == 0) wred[oc * 4 + wv] = rs;
  }

  {
    int4* dst = reinterpret_cast<int4*>(x1) +
                ((size_t)b * 1024 + (r0 + lr) * 32 + pc) * 8;
    const int4* src = reinterpret_cast<const int4*>(pk);
#pragma unroll
    for (int j2 = 0; j2 < 8; ++j2) dst[j2] = src[j2];
  }
  __syncthreads();
  if (t < 64) {
    const float s = wred[t * 4] + wred[t * 4 + 1] + wred[t * 4 + 2] + wred[t * 4 + 3];
    part2[((size_t)quarter * 64 + t) * 128 + b] = s;
  }
}

// ---------------- K2: selection (redundant per block) + weight prep (block j) -----
// grid 48 blocks x 256 thr. part2 layout [quarter*64 + c][128 b].
__global__ __launch_bounds__(256) void k2_selprep(
    const float* __restrict__ part2, const float* __restrict__ gate_w,
    const float* __restrict__ w2, const float* __restrict__ b2,
    int* __restrict__ sel, unsigned short* __restrict__ w2t,
    float* __restrict__ b2s) {
  const int t = threadIdx.x;
  const int j = blockIdx.x;  // slot = rank
  __shared__ float red[64 * 33];
  __shared__ float sig[64];
  __shared__ float sc[256];
  __shared__ int pick;

  // Full coalesced reduction of part2 (32768 floats = 8192 float4).
  // float4 id f = q*256+t: channel c = (q&7)*8 + (t>>5); col4 = t&31.
  float prt[8];
#pragma unroll
  for (int k = 0; k < 8; ++k) prt[k] = 0.f;
  const float4* pv = reinterpret_cast<const float4*>(part2);
#pragma unroll
  for (int q = 0; q < 32; ++q) {
    const float4 v = pv[q * 256 + t];
    prt[q & 7] += v.x + v.y + v.z + v.w;
  }
#pragma unroll
  for (int k = 0; k < 8; ++k)
    red[(k * 8 + (t >> 5)) * 33 + (t & 31)] = prt[k];
  __syncthreads();
  if (t < 64) {
    float s = 0.f;
    for (int i = 0; i < 32; ++i) s += red[t * 33 + i];
    sig[t] = s * (1.0f / 131072.0f);
  }
  __syncthreads();

  {  // gate logits (softplus monotone -> rank by logits)
    float lg = 0.f;
#pragma unroll 8
    for (int i = 0; i < 64; ++i) lg += gate_w[t * 64 + i] * sig[i];
    sc[t] = lg;
  }
  __syncthreads();

  {  // rank = position in desc sort with index tiebreak (top_k order)
    const float v = sc[t];
    int r = 0;
    for (int i = 0; i < 256; ++i) {
      const float vi = sc[i];
      r += (vi > v) || (vi == v && i < t);
    }
    if (r == j) pick = t;
    if (j == 0 && r < NSEL) sel[r] = t;
  }
  __syncthreads();

  const int c = pick;
  if (t == 0) b2s[j] = b2[c];
  for (int id = t; id < 576; id += 256) {
    const float v = w2[(size_t)c * 576 + id];
    const int ic = id / 9;
    const int s = id - ic * 9;
    w2t[((size_t)s * 48 + j) * 64 + ic] = f2bf(v);
  }
}

// ---------------- K3: conv2 via 9-shift bf16 MFMA + bias + ReLU + maxpool ---------
__global__ __launch_bounds__(256) void k3_conv2(
    const unsigned short* __restrict__ x1, const unsigned short* __restrict__ w2t,
    const float* __restrict__ b2s, unsigned short* __restrict__ pooledt) {
  const int b = blockIdx.x, quarter = blockIdx.y;
  const int t = threadIdx.x;
  const int w = t >> 6, l = t & 63;
  const int q4 = l >> 4, ln15 = l & 15;
  __shared__ short xt[20480];  // 10 rows x 32 cols x 64 ic bf16, 16B-slot swizzled

  const int r0 = quarter * 8;

  for (int q = 0; q < 10; ++q) {
    const int S = (w * 10 + q) * 64 + l;
    const int pix = S >> 3, slot = S & 7;
    const int row = pix >> 5, col = pix & 31;
    int gr = r0 - 1 + row;
    gr = gr < 0 ? 0 : (gr > 31 ? 31 : gr);
    const unsigned short* gsrc =
        x1 + ((size_t)(b * 1024 + gr * 32 + col) * 64) + (slot ^ (pix & 7)) * 8;
    gl_lds16((const void*)gsrc, (void*)&xt[(w * 10 + q) * 512]);
  }
  __syncthreads();

  f4 acc[4][3];
  const f4 fz = {0.f, 0.f, 0.f, 0.f};
#pragma unroll
  for (int i = 0; i < 4; ++i)
#pragma unroll
    for (int nt = 0; nt < 3; ++nt) acc[i][nt] = fz;

  const int w4 = w * 4;
  const sh8 zz = {0, 0, 0, 0, 0, 0, 0, 0};

#pragma unroll
  for (int kh = 0; kh < 3; ++kh)
#pragma unroll
    for (int kw = 0; kw < 3; ++kw) {
      const int sh = kh * 3 + kw;
      sh8 bf[3][2];
#pragma unroll
      for (int nt = 0; nt < 3; ++nt)
#pragma unroll
        for (int ks = 0; ks < 2; ++ks)
          bf[nt][ks] = *reinterpret_cast<const sh8*>(
              w2t + ((size_t)(sh * 48 + nt * 16 + ln15) * 64 + ks * 32 + q4 * 8));
#pragma unroll
      for (int i = 0; i < 4; ++i) {
        const int mt = w4 + i;
        const int lsr = (mt >> 1) + kh;
        const int gsr = r0 + lsr - 1;
        if ((unsigned)gsr < 32u) {
          const int w_ = (mt & 1) * 16 + ln15;
          const int cc = w_ + kw - 1;
          const bool cv = (unsigned)cc < 32u;
          int p = lsr * 32 + cc;
          p = p < 0 ? 0 : (p > 319 ? 319 : p);
#pragma unroll
          for (int ks = 0; ks < 2; ++ks) {
            sh8 af = *reinterpret_cast<const sh8*>(
                &xt[p * 64 + (((ks << 2) | q4) ^ (p & 7)) * 8]);
            af = cv ? af : zz;
            acc[i][0] = __builtin_amdgcn_mfma_f32_16x16x32_bf16(af, bf[0][ks], acc[i][0], 0, 0, 0);
            acc[i][1] = __builtin_amdgcn_mfma_f32_16x16x32_bf16(af, bf[1][ks], acc[i][1], 0, 0, 0);
            acc[i][2] = __builtin_amdgcn_mfma_f32_16x16x32_bf16(af, bf[2][ks], acc[i][2], 0, 0, 0);
          }
        }
      }
    }

  __syncthreads();  // done reading xt; reuse as pooled staging [48 oc][64 p]

  float bias[3];
#pragma unroll
  for (int nt = 0; nt < 3; ++nt) bias[nt] = b2s[nt * 16 + ln15];

  unsigned short* ps = reinterpret_cast<unsigned short*>(xt);
#pragma unroll
  for (int a = 0; a < 2; ++a) {
#pragma unroll
    for (int nt = 0; nt < 3; ++nt) {
      const f4 A = acc[a][nt], Bv = acc[a + 2][nt];
#pragma unroll
      for (int pr = 0; pr < 2; ++pr) {
        float m = fmaxf(fmaxf(A[pr * 2], A[pr * 2 + 1]),
                        fmaxf(Bv[pr * 2], Bv[pr * 2 + 1]));
        m = fmaxf(m + bias[nt], 0.f);
        const int pl = w * 16 + a * 8 + q4 * 2 + pr;
        ps[(nt * 16 + ln15) * 64 + pl] = f2bf(m);
      }
    }
  }
  __syncthreads();

  const int4* psv = reinterpret_cast<const int4*>(xt);
  int4* po = reinterpret_cast<int4*>(pooledt);
  for (int c = t; c < 384; c += 256) {
    const int j = c >> 3, sub = c & 7;
    po[(size_t)(j * 32 + quarter * 8 + sub) * 128 + b] = psv[c];
  }
}

// ---------------- K4: bf16 MFMA GEMM partials. BM=128, BN=32, K split 16 ----------
__global__ __launch_bounds__(256) void k4_fc(
    const unsigned short* __restrict__ pooledt, const float* __restrict__ fc_w,
    const int* __restrict__ sel, float* __restrict__ fcpart) {
  const int ntile = blockIdx.x;  // 0..31  (BN=32)
  const int ks = blockIdx.y;     // 0..15  (K chunk = 768 = 3 channels)
  const int t = threadIdx.x;
  const int w = t >> 6, l = t & 63;

  __shared__ short Ab[2][8192];  // [ko 8][m 128][8] bf16
  __shared__ short Bb[2][2048];  // [ko 8][n 32][8] bf16

  f4 acc[2][2];
  const f4 fzero = {0.f, 0.f, 0.f, 0.f};
#pragma unroll
  for (int i = 0; i < 2; ++i)
#pragma unroll
    for (int j = 0; j < 2; ++j) acc[i][j] = fzero;

  int ch[3];
#pragma unroll
  for (int i = 0; i < 3; ++i)
    ch[i] = __builtin_amdgcn_readfirstlane(sel[ks * 3 + i]);

  const int n0 = ntile * 32;
  const int nl = t & 31;
  int ng = n0 + nl; if (ng > 999) ng = 999;  // clamp tail rows (k5 ignores)
  const int kh = t >> 5;  // 0..7 k-oct
  const float* wrow = fc_w + (size_t)ng * 65536 + kh * 8;

  const int4* pt = reinterpret_cast<const int4*>(pooledt);
  const int kb0 = ks * 96;

  int4 av[4];
  float4 bv0, bv1;

  {  // stage tile 0
#pragma unroll
    for (int it = 0; it < 4; ++it) {
      const int s = it * 256 + t, ko = s >> 7, m = s & 127;
      av[it] = pt[(kb0 + ko) * 128 + m];
    }
    const float* bp = wrow + ch[0] * 256;
    bv0 = *reinterpret_cast<const float4*>(bp);
    bv1 = *reinterpret_cast<const float4*>(bp + 4);
#pragma unroll
    for (int it = 0; it < 4; ++it)
      *reinterpret_cast<int4*>(&Ab[0][(it * 256 + t) * 8]) = av[it];
    int4 bw;
    bw.x = f2bf(bv0.x) | ((unsigned)f2bf(bv0.y) << 16);
    bw.y = f2bf(bv0.z) | ((unsigned)f2bf(bv0.w) << 16);
    bw.z = f2bf(bv1.x) | ((unsigned)f2bf(bv1.y) << 16);
    bw.w = f2bf(bv1.z) | ((unsigned)f2bf(bv1.w) << 16);
    *reinterpret_cast<int4*>(&Bb[0][(kh * 32 + nl) * 8]) = bw;
  }
  __syncthreads();

  for (int tt = 0; tt < 12; ++tt) {
    const int cur = tt & 1, nxt = cur ^ 1;
    if (tt < 11) {
      const int tn = tt + 1;
#pragma unroll
      for (int it = 0; it < 4; ++it) {
        const int s = it * 256 + t, ko = s >> 7, m = s & 127;
        av[it] = pt[(kb0 + tn * 8 + ko) * 128 + m];
      }
      const float* bp = wrow + ch[tn >> 2] * 256 + (tn & 3) * 64;
      bv0 = *reinterpret_cast<const float4*>(bp);
      bv1 = *reinterpret_cast<const float4*>(bp + 4);
    }

#pragma unroll
    for (int s2 = 0; s2 < 2; ++s2) {
      const int kg = s2 * 4 + (l >> 4);
      const int m0 = w * 32 + (l & 15);
      sh8 a0 = *reinterpret_cast<const sh8*>(&Ab[cur][(kg * 128 + m0) * 8]);
      sh8 a1 = *reinterpret_cast<const sh8*>(&Ab[cur][(kg * 128 + m0 + 16) * 8]);
      sh8 b0 = *reinterpret_cast<const sh8*>(&Bb[cur][(kg * 32 + (l & 15)) * 8]);
      sh8 b1 = *reinterpret_cast<const sh8*>(&Bb[cur][(kg * 32 + 16 + (l & 15)) * 8]);
      acc[0][0] = __builtin_amdgcn_mfma_f32_16x16x32_bf16(a0, b0, acc[0][0], 0, 0, 0);
      acc[0][1] = __builtin_amdgcn_mfma_f32_16x16x32_bf16(a0, b1, acc[0][1], 0, 0, 0);
      acc[1][0] = __builtin_amdgcn_mfma_f32_16x16x32_bf16(a1, b0, acc[1][0], 0, 0, 0);
      acc[1][1] = __builtin_amdgcn_mfma_f32_16x16x32_bf16(a1, b1, acc[1][1], 0, 0, 0);
    }

    if (tt < 11) {
#pragma unroll
      for (int it = 0; it < 4; ++it)
        *reinterpret_cast<int4*>(&Ab[nxt][(it * 256 + t) * 8]) = av[it];
      int4 bw;
      bw.x = f2bf(bv0.x) | ((unsigned)f2bf(bv0.y) << 16);
      bw.y = f2bf(bv0.z) | ((unsigned)f2bf(bv0.w) << 16);
      bw.z = f2bf(bv1.x) | ((unsigned)f2bf(bv1.y) << 16);
      bw.w = f2bf(bv1.z) | ((unsigned)f2bf(bv1.w) << 16);
      *reinterpret_cast<int4*>(&Bb[nxt][(kh * 32 + nl) * 8]) = bw;
    }
    __syncthreads();
  }

  const int r0 = (l >> 4) * 4;
#pragma unroll
  for (int fm = 0; fm < 2; ++fm)
#pragma unroll
    for (int fn = 0; fn < 2; ++fn)
#pragma unroll
      for (int r = 0; r < 4; ++r) {
        const int m = w * 32 + fm * 16 + r0 + r;
        const int nc = n0 + fn * 16 + (l & 15);
        fcpart[(((size_t)ks * 128 + m) << 10) + nc] = acc[fm][fn][r];
      }
}

// ---------------- K5: reduce K-split partials + bias ------------------------------
__global__ __launch_bounds__(256) void k5_reduce(
    const float* __restrict__ fcpart, const float* __restrict__ fc_b,
    float* __restrict__ out) {
  const int id = blockIdx.x * 256 + threadIdx.x;  // 0..127999
  const int b = id / 1000;
  const int n = id - b * 1000;
  float s = fc_b[n];
#pragma unroll
  for (int ks = 0; ks < 16; ++ks)
    s += fcpart[(((size_t)ks * 128 + b) << 10) + n];
  out[id] = s;
}

extern "C" void kernel_launch(void* const* d_in, const int* in_sizes, int n_in,
                              void* d_out, int out_size, void* d_ws, size_t ws_size,
                              hipStream_t stream) {
  (void)in_sizes; (void)n_in; (void)out_size; (void)ws_size;
  const float* x0     = (const float*)d_in[0];
  const float* w1     = (const float*)d_in[1];
  const float* b1     = (const float*)d_in[2];
  const float* gate_w = (const float*)d_in[3];
  const float* w2     = (const float*)d_in[4];
  const float* b2     = (const float*)d_in[5];
  const float* fc_w   = (const float*)d_in[6];
  const float* fc_b   = (const float*)d_in[7];
  float* out = (float*)d_out;

  char* ws = (char*)d_ws;
  unsigned short* x1      = (unsigned short*)(ws);             // 16,777,216 B
  unsigned short* pooledt = (unsigned short*)(ws + 16777216);  //  3,145,728 B
  float*          part2   = (float*)(ws + 19922944);           //    131,072 B
  int*            sel     = (int*)  (ws + 20054016);           //        256 B
  unsigned short* w2t     = (unsigned short*)(ws + 20054272);  //     55,296 B
  float*          b2s     = (float*)(ws + 20109568);           //        768 B
  float*          fcpart  = (float*)(ws + 20110336);           //  8,388,608 B

  hipLaunchKernelGGL(k1_conv1, dim3(128, 4), dim3(256), 0, stream, x0, w1, b1, x1, part2);
  hipLaunchKernelGGL(k2_selprep, dim3(48), dim3(256), 0, stream, part2, gate_w, w2, b2, sel, w2t, b2s);
  hipLaunchKernelGGL(k3_conv2, dim3(128, 4), dim3(256), 0, stream, x1, w2t, b2s, pooledt);
  hipLaunchKernelGGL(k4_fc, dim3(32, 16), dim3(256), 0, stream, pooledt, fc_w, sel, fcpart);
  hipLaunchKernelGGL(k5_reduce, dim3(500), dim3(256), 0, stream, fcpart, fc_b, out);
}